// Round 21
// baseline (162.446 us; speedup 1.0000x reference)
//
#include <hip/hip_runtime.h>
#include <cstdint>
#include <cstddef>

#define C_DIM 768
#define NPIX  1024
#define B_DIM 16
#define NTOT  16384
#define KT_N  12      // 768/64 K-tiles (K-step 64 for i8 MFMA)
#define MT_N  6       // 768/128 M-tiles (A-blob layout AND block rows)
#define JT_N  128     // 16384/128 N-tiles
#define TAU   2.0e-3f
#define BCAP  64                       // record slots per block (expected ~7)
#define NBLK  (3 * MT_N * JT_N)        // 2304 branch blocks
#define PLANE_B (C_DIM * C_DIM)   // bytes per i8 weight plane
#define TILE_B  8192              // bytes per 128x64 i8 tile
// prep_all block ranges
#define PREP_SPIKE_BLKS (JT_N * KT_N)         // 1536
#define PREP_W_BLKS     576                   // 4*768*48 threads / 256
#define PREP_BN_BLKS    12

typedef __attribute__((ext_vector_type(4)))  int   int4v;
typedef __attribute__((ext_vector_type(16))) char  char16v;

__device__ __forceinline__ void gload16(const void* g, void* l) {
    __builtin_amdgcn_global_load_lds(
        (const __attribute__((address_space(1))) unsigned int*)g,
        (__attribute__((address_space(3))) unsigned int*)l, 16, 0, 0);
}

// ---------------------------------------------------------------------------
// Fused prep: [0,1536) spikes | [1536,2112) weights | [2112,2124) BN affine.
// ---------------------------------------------------------------------------
__global__ __launch_bounds__(256) void prep_all(
    const float* __restrict__ x,
    const float* __restrict__ w0, const float* __restrict__ w1,
    const float* __restrict__ w2, const float* __restrict__ w3,
    const float* __restrict__ qg, const float* __restrict__ qb,
    const float* __restrict__ qm, const float* __restrict__ qv,
    const float* __restrict__ kg, const float* __restrict__ kb,
    const float* __restrict__ km, const float* __restrict__ kv,
    const float* __restrict__ vg, const float* __restrict__ vb,
    const float* __restrict__ vm, const float* __restrict__ vv,
    const float* __restrict__ pg, const float* __restrict__ pb,
    const float* __restrict__ pm, const float* __restrict__ pv,
    char* __restrict__ xs, char* __restrict__ wall,
    float* __restrict__ invt, float* __restrict__ biast)
{
    const int blk = blockIdx.x;
    if (blk < PREP_SPIKE_BLKS) {
        const int jt = blk / KT_N, kt = blk - jt * KT_N;
        const int b  = jt >> 3;
        const int n0 = (jt & 7) * 128;
#pragma unroll
        for (int i = 0; i < 2; ++i) {
            int q = threadIdx.x + i * 256;    // (kg, col)
            int kgc = q >> 7, col = q & 127;
            char16v sv;
#pragma unroll
            for (int e = 0; e < 16; ++e) {
                float xv = x[((size_t)b * C_DIM + (kt * 64 + kgc * 16 + e)) * NPIX + n0 + col];
                sv[e] = (xv >= 2.0f) ? (char)1 : (char)0;
            }
            *(char16v*)(xs + (size_t)(jt * KT_N + kt) * TILE_B + (size_t)q * 16) = sv;
        }
    } else if (blk < PREP_SPIKE_BLKS + PREP_W_BLKS) {
        int t = (blk - PREP_SPIKE_BLKS) * 256 + threadIdx.x;  // 0..147455
        int set = t / (C_DIM * 48);
        int rem = t - set * (C_DIM * 48);
        int o = rem / 48, c16 = rem - (rem / 48) * 48;        // row, 16-col chunk
        const float* w = set == 0 ? w0 : set == 1 ? w1 : set == 2 ? w2 : w3;
        char* pl = wall + (size_t)set * 2 * PLANE_B;
        char16v H, L;
#pragma unroll
        for (int e = 0; e < 16; ++e) {
            float wv = w[(size_t)o * C_DIM + c16 * 16 + e];   // coalesced 64B/thread
            int w16 = (int)lrintf(wv * 16384.0f);
            w16 = w16 > 32639 ? 32639 : (w16 < -32639 ? -32639 : w16);
            int hi = (w16 + 128) >> 8;
            int lo = w16 - (hi << 8);
            H[e] = (char)hi;
            L[e] = (char)lo;
        }
        int mt = o >> 7, m = o & 127;
        int kt = c16 >> 2, kgc = c16 & 3;
        size_t base = (size_t)(kt * MT_N + mt) * TILE_B + kgc * 2048 + (size_t)m * 16;
        *(char16v*)(pl + base)           = H;
        *(char16v*)(pl + PLANE_B + base) = L;
    } else {
        int i = (blk - PREP_SPIKE_BLKS - PREP_W_BLKS) * 256 + threadIdx.x;  // 0..3071
        if (i >= 4 * C_DIM) return;
        int set = i / C_DIM, o = i - set * C_DIM;
        const float* g = set == 0 ? qg : set == 1 ? kg : set == 2 ? vg : pg;
        const float* b = set == 0 ? qb : set == 1 ? kb : set == 2 ? vb : pb;
        const float* m = set == 0 ? qm : set == 1 ? km : set == 2 ? vm : pm;
        const float* v = set == 0 ? qv : set == 1 ? kv : set == 2 ? vv : pv;
        float inv = g[o] / sqrtf(v[o] + 1e-5f);
        invt[i]  = inv;
        biast[i] = b[o] - m[o] * inv;
    }
}

// ---------------------------------------------------------------------------
// Branch GEMMs (q,k,v via blockIdx.z), 256 thr = 4 waves (2M x 2N),
// WAVE TILE 64x64 (32 MFMA/wave per k-tile -> sync-per-MFMA halved),
// block tile 128x128. A+B stages are straight contiguous copies
// (A_hi 8K | A_lo 8K | B 8K = 24KB/stage, 2 stages). Counted-vmcnt
// pipeline: vmcnt(6) never 0 mid-loop, 2 raw barriers/iter, lgkm fence.
// Band records -> per-block regions via LDS counter (no global atomics).
// ---------------------------------------------------------------------------
__global__ __launch_bounds__(256, 2) void branch_mfma(
    const char* __restrict__ wall, const char* __restrict__ xsblob,
    const float* __restrict__ invt, const float* __restrict__ biast,
    char* __restrict__ sall,
    unsigned int* __restrict__ cntArr, unsigned int* __restrict__ recsB)
{
    __shared__ char stage[2][24576];   // [A_hi 8K][A_lo 8K][B 8K]
    __shared__ unsigned int lcnt;
    const int jt = blockIdx.x, mt = blockIdx.y, z = blockIdx.z;  // mt: 128-row tiles
    const int tid = threadIdx.x;
    const int lane = tid & 63, wid = tid >> 6;
    const int wm = wid >> 1, wn = wid & 1;       // 2(M) x 2(N) waves, 64x64 each
    const int lr = lane & 15, kgl = lane >> 4;
    const char* wblob = wall + (size_t)z * 2 * PLANE_B;
    char* sblob = sall + (size_t)z * (size_t)C_DIM * NTOT;
    const float* invz  = invt  + z * C_DIM;
    const float* biasz = biast + z * C_DIM;
    const unsigned int blk = ((unsigned)z * MT_N + mt) * JT_N + jt;

#define STG(buf, ktA) do {                                                     \
        const char* Ab_ = wblob + (size_t)((ktA) * MT_N + mt) * TILE_B;        \
        const char* Bb_ = xsblob + (size_t)(jt * KT_N + (ktA)) * TILE_B;       \
        char* d_ = stage[buf];                                                 \
        gload16(Ab_ + (size_t)tid * 16,                  d_ + tid * 16);       \
        gload16(Ab_ + 4096 + (size_t)tid * 16,           d_ + 4096 + tid * 16);\
        gload16(Ab_ + PLANE_B + (size_t)tid * 16,        d_ + 8192 + tid * 16);\
        gload16(Ab_ + PLANE_B + 4096 + (size_t)tid * 16, d_ + 12288 + tid * 16);\
        gload16(Bb_ + (size_t)tid * 16,                  d_ + 16384 + tid * 16);\
        gload16(Bb_ + 4096 + (size_t)tid * 16,           d_ + 20480 + tid * 16);\
    } while (0)

    int4v acch[4][4], accl[4][4];
#pragma unroll
    for (int a = 0; a < 4; ++a)
#pragma unroll
        for (int b2 = 0; b2 < 4; ++b2) {
            acch[a][b2] = (int4v){0, 0, 0, 0};
            accl[a][b2] = (int4v){0, 0, 0, 0};
        }

    STG(0, 0);
    STG(1, 1);
    if (tid == 0) lcnt = 0;
    int cur = 0;
    const int arow = (wm * 64 + lr) * 16;        // + fm*256
    const int brow = (wn * 64 + lr) * 16;        // + fn*256
    for (int kt = 0; kt < KT_N; ++kt) {
        if (kt + 1 < KT_N) asm volatile("s_waitcnt vmcnt(6)");
        else               asm volatile("s_waitcnt vmcnt(0)");
        __builtin_amdgcn_s_barrier();            // stage(kt) visible
        __builtin_amdgcn_sched_barrier(0);
        const char* st = stage[cur];
        int4v ah[4], al[4], bfr[4];
#pragma unroll
        for (int fm = 0; fm < 4; ++fm) {
            ah[fm] = *(const int4v*)&st[kgl * 2048 + arow + fm * 256];
            al[fm] = *(const int4v*)&st[8192 + kgl * 2048 + arow + fm * 256];
        }
#pragma unroll
        for (int fn = 0; fn < 4; ++fn)
            bfr[fn] = *(const int4v*)&st[16384 + kgl * 2048 + brow + fn * 256];
        __builtin_amdgcn_sched_barrier(0);
        asm volatile("s_waitcnt lgkmcnt(0)");
        __builtin_amdgcn_sched_barrier(0);
        __builtin_amdgcn_s_barrier();            // all waves done reading buf
        if (kt + 2 < KT_N) STG(cur, kt + 2);     // overwrite safe
        __builtin_amdgcn_s_setprio(1);
#pragma unroll
        for (int fm = 0; fm < 4; ++fm)
#pragma unroll
            for (int fn = 0; fn < 4; ++fn) {
                acch[fm][fn] = __builtin_amdgcn_mfma_i32_16x16x64_i8(ah[fm], bfr[fn], acch[fm][fn], 0, 0, 0);
                accl[fm][fn] = __builtin_amdgcn_mfma_i32_16x16x64_i8(al[fm], bfr[fn], accl[fm][fn], 0, 0, 0);
            }
        __builtin_amdgcn_s_setprio(0);
        cur ^= 1;
    }
#undef STG

    // ---- epilogue: BN + spike in registers; band records -> per-block region
    unsigned int pk[4][4];
#pragma unroll
    for (int fm = 0; fm < 4; ++fm)
#pragma unroll
        for (int fn = 0; fn < 4; ++fn) {
            unsigned int p = 0;
#pragma unroll
            for (int r = 0; r < 4; ++r) {
                int o = mt * 128 + wm * 64 + fm * 16 + kgl * 4 + r;
                int vi = acch[fm][fn][r] * 256 + accl[fm][fn][r];
                float y = (float)vi * 6.103515625e-05f;    // *2^-14, exact
                float ybn = y * invz[o] + biasz[o];
                if (ybn >= 2.0f) p |= (1u << (r * 8));
                if (fabsf(ybn - 2.0f) < TAU) {
                    unsigned int idx = atomicAdd(&lcnt, 1u);   // LDS atomic
                    if (idx < BCAP) {
                        int j = jt * 128 + wn * 64 + fn * 16 + lr;
                        recsB[(size_t)blk * BCAP + idx] =
                            ((unsigned)z << 24) | ((unsigned)o << 14) | (unsigned)j;
                    }
                }
            }
            pk[fm][fn] = p;
        }

    // shfl-transpose pack -> direct blob stores.
    // Receiver (kgl, lr) owns chunks (fm = kgl, fn = 0..3):
    //   chunk byte e = j*4+r  = pk[kgl][fn] word from sender group j.
    //   kt2 = mt*2 + wm, kg2 = kgl, col = wn*64 + fn*16 + lr.
#pragma unroll
    for (int fn = 0; fn < 4; ++fn) {
        unsigned int got[4];
#pragma unroll
        for (int t = 0; t < 4; ++t) {
            int sel = (kgl + t) & 3;
            unsigned int send = sel == 0 ? pk[0][fn] : sel == 1 ? pk[1][fn]
                              : sel == 2 ? pk[2][fn] : pk[3][fn];
            int src = (((kgl - t) & 3) << 4) + lr;
            got[t] = (unsigned int)__shfl((int)send, src);
        }
        unsigned int part[4];
#pragma unroll
        for (int j = 0; j < 4; ++j) {
            int tsel = (kgl - j) & 3;
            part[j] = tsel == 0 ? got[0] : tsel == 1 ? got[1]
                    : tsel == 2 ? got[2] : got[3];
        }
        int4v chunk = (int4v){(int)part[0], (int)part[1], (int)part[2], (int)part[3]};
        int col = wn * 64 + fn * 16 + lr;
        size_t off = (size_t)(jt * KT_N + mt * 2 + wm) * TILE_B
                   + (size_t)kgl * 2048 + (size_t)col * 16;
        *(int4v*)(sblob + off) = chunk;
    }
    __syncthreads();
    if (tid == 0) {
        unsigned int c = lcnt;
        cntArr[blk] = c > BCAP ? BCAP : c;
    }
}

// ---------------------------------------------------------------------------
// Pass-2 fixup over per-block record regions, SLOT-MAJOR pair distribution
// (slot = p / NBLK). Bit-exact numpy fp32 re-resolution (skip-zero exact).
// ---------------------------------------------------------------------------
__global__ __launch_bounds__(256) void fixup(
    const char* __restrict__ xs,
    const float* __restrict__ wq, const float* __restrict__ wk, const float* __restrict__ wv,
    const float* __restrict__ qg, const float* __restrict__ qb, const float* __restrict__ qm, const float* __restrict__ qv,
    const float* __restrict__ kg, const float* __restrict__ kb2, const float* __restrict__ km, const float* __restrict__ kvr,
    const float* __restrict__ vg, const float* __restrict__ vb, const float* __restrict__ vm, const float* __restrict__ vv,
    char* __restrict__ sq, char* __restrict__ sk, char* __restrict__ sv,
    const unsigned int* __restrict__ cntArr, const unsigned int* __restrict__ recsB)
{
#pragma clang fp contract(off)
    __shared__ float cw[4][C_DIM];
    const int lane = threadIdx.x & 63;
    const int wvid = threadIdx.x >> 6;
    const int gwave = blockIdx.x * 4 + wvid;
    const int nwaves = gridDim.x * 4;
    const int npairs = NBLK * BCAP;

    for (int p = gwave; p < npairs; p += nwaves) {
        int slot = p / NBLK;            // slow index: populated slots first
        int reg  = p - slot * NBLK;
        if ((unsigned)slot >= cntArr[reg]) continue;
        unsigned int rec = recsB[(size_t)reg * BCAP + slot];
        int plane = rec >> 24, o = (rec >> 14) & 1023, j = rec & 16383;
        int jt = j >> 7, col = j & 127;
        const float* w = plane == 0 ? wq : plane == 1 ? wk : wv;
        int base = 0;
#pragma unroll
        for (int cc = 0; cc < 12; ++cc) {
            int c = cc * 64 + lane;
            char s = xs[(size_t)(jt * KT_N + (c >> 6)) * TILE_B
                        + ((c >> 4) & 3) * 2048 + col * 16 + (c & 15)];
            float wvv = w[(size_t)o * C_DIM + c];
            bool act = (s != 0);
            unsigned long long m = __ballot(act);
            int pos = __popcll(m & ((1ull << lane) - 1ull));
            if (act) cw[wvid][base + pos] = wvv;
            base += __popcll(m);
        }
        __builtin_amdgcn_s_waitcnt(0);       // wave-coherent LDS
        if (lane == 0) {
            float s = 0.0f;
            for (int i = 0; i < base; ++i) s = s + cw[wvid][i];   // strict order
            const float* g  = plane == 0 ? qg : plane == 1 ? kg : vg;
            const float* be = plane == 0 ? qb : plane == 1 ? kb2 : vb;
            const float* me = plane == 0 ? qm : plane == 1 ? km : vm;
            const float* va = plane == 0 ? qv : plane == 1 ? kvr : vv;
            float invv = g[o] / sqrtf(va[o] + 1e-5f);
            float t1 = me[o] * invv;
            float bias = be[o] - t1;
            float t3 = s * invv;
            float ybn = t3 + bias;
            char spv = (ybn >= 2.0f) ? (char)1 : (char)0;
            char* blob = plane == 0 ? sq : plane == 1 ? sk : sv;
            blob[(size_t)(jt * KT_N + (o >> 6)) * TILE_B
                 + ((o >> 4) & 3) * 2048 + col * 16 + (o & 15)] = spv;
        }
    }
}

// ---------------------------------------------------------------------------
// maskb[b][c] = OR_n (sk & sv), bytes {0,1}
// ---------------------------------------------------------------------------
__global__ __launch_bounds__(256) void kv_mask_blob(
    const char* __restrict__ sk, const char* __restrict__ sv,
    unsigned char* __restrict__ maskb)
{
    const int kt = blockIdx.x, b = blockIdx.y;
    const int t = threadIdx.x;
    const int kgc = t >> 6;
    const int col0 = (t & 63) * 2;
    __shared__ unsigned int lmask[4][4];
    if (t < 16) lmask[t >> 2][t & 3] = 0;
    __syncthreads();
    uint4 acc = make_uint4(0, 0, 0, 0);
    for (int jti = 0; jti < 8; ++jti) {
        size_t base = (size_t)((b * 8 + jti) * KT_N + kt) * TILE_B + kgc * 2048;
#pragma unroll
        for (int cc = 0; cc < 2; ++cc) {
            uint4 kk = *(const uint4*)(sk + base + (size_t)(col0 + cc) * 16);
            uint4 vv = *(const uint4*)(sv + base + (size_t)(col0 + cc) * 16);
            acc.x |= (kk.x & vv.x); acc.y |= (kk.y & vv.y);
            acc.z |= (kk.z & vv.z); acc.w |= (kk.w & vv.w);
        }
    }
    if (acc.x) atomicOr(&lmask[kgc][0], acc.x);
    if (acc.y) atomicOr(&lmask[kgc][1], acc.y);
    if (acc.z) atomicOr(&lmask[kgc][2], acc.z);
    if (acc.w) atomicOr(&lmask[kgc][3], acc.w);
    __syncthreads();
    if (t < 64) {
        int kg2 = t >> 4, e = t & 15;
        unsigned int dw = lmask[kg2][e >> 2];
        unsigned char byte = (dw >> ((e & 3) * 8)) & 0xFF;
        maskb[(size_t)b * C_DIM + kt * 64 + t] = byte ? 1 : 0;
    }
}

// ---------------------------------------------------------------------------
// Final projection: out = (wp·(sq & mask) + bp)*inv + bias + x
// Same 128x128 / 64x64-wave counted-vmcnt pipeline; mask pre-staged to LDS.
// ---------------------------------------------------------------------------
__global__ __launch_bounds__(256, 2) void final_mfma(
    const char* __restrict__ wblob, const char* __restrict__ sqblob,
    const unsigned char* __restrict__ maskb,
    const float* __restrict__ x, const float* __restrict__ bp,
    const float* __restrict__ invt, const float* __restrict__ biast,
    float* __restrict__ out)
{
    __shared__ char stage[2][24576];
    __shared__ char mlds[768];
    const int jt = blockIdx.x, mt = blockIdx.y;
    const int tid = threadIdx.x;
    const int lane = tid & 63, wid = tid >> 6;
    const int wm = wid >> 1, wn = wid & 1;
    const int lr = lane & 15, kgl = lane >> 4;
    const int b = jt >> 3;
    const float* invp  = invt  + 3 * C_DIM;
    const float* biasp = biast + 3 * C_DIM;

#define STG(buf, ktA) do {                                                     \
        const char* Ab_ = wblob + (size_t)((ktA) * MT_N + mt) * TILE_B;        \
        const char* Bb_ = sqblob + (size_t)(jt * KT_N + (ktA)) * TILE_B;       \
        char* d_ = stage[buf];                                                 \
        gload16(Ab_ + (size_t)tid * 16,                  d_ + tid * 16);       \
        gload16(Ab_ + 4096 + (size_t)tid * 16,           d_ + 4096 + tid * 16);\
        gload16(Ab_ + PLANE_B + (size_t)tid * 16,        d_ + 8192 + tid * 16);\
        gload16(Ab_ + PLANE_B + 4096 + (size_t)tid * 16, d_ + 12288 + tid * 16);\
        gload16(Bb_ + (size_t)tid * 16,                  d_ + 16384 + tid * 16);\
        gload16(Bb_ + 4096 + (size_t)tid * 16,           d_ + 20480 + tid * 16);\
    } while (0)

    int4v acch[4][4], accl[4][4];
#pragma unroll
    for (int a = 0; a < 4; ++a)
#pragma unroll
        for (int b2 = 0; b2 < 4; ++b2) {
            acch[a][b2] = (int4v){0, 0, 0, 0};
            accl[a][b2] = (int4v){0, 0, 0, 0};
        }

    if (tid < 48)
        *(int4v*)&mlds[tid * 16] = *(const int4v*)(maskb + (size_t)b * C_DIM + tid * 16);
    STG(0, 0);
    STG(1, 1);
    __syncthreads();                 // one-time full drain (mlds + stages 0,1)
    int cur = 0;
    const int arow = (wm * 64 + lr) * 16;
    const int brow = (wn * 64 + lr) * 16;
    for (int kt = 0; kt < KT_N; ++kt) {
        if (kt + 1 < KT_N) asm volatile("s_waitcnt vmcnt(6)");
        else               asm volatile("s_waitcnt vmcnt(0)");
        __builtin_amdgcn_s_barrier();
        __builtin_amdgcn_sched_barrier(0);
        const char* st = stage[cur];
        int4v ah[4], al[4], bfr[4];
#pragma unroll
        for (int fm = 0; fm < 4; ++fm) {
            ah[fm] = *(const int4v*)&st[kgl * 2048 + arow + fm * 256];
            al[fm] = *(const int4v*)&st[8192 + kgl * 2048 + arow + fm * 256];
        }
#pragma unroll
        for (int fn = 0; fn < 4; ++fn)
            bfr[fn] = *(const int4v*)&st[16384 + kgl * 2048 + brow + fn * 256];
        int4v mp = *(const int4v*)&mlds[kt * 64 + kgl * 16];
        __builtin_amdgcn_sched_barrier(0);
        asm volatile("s_waitcnt lgkmcnt(0)");
        __builtin_amdgcn_sched_barrier(0);
        __builtin_amdgcn_s_barrier();
        if (kt + 2 < KT_N) STG(cur, kt + 2);
#pragma unroll
        for (int fn = 0; fn < 4; ++fn) bfr[fn] &= mp;
        __builtin_amdgcn_s_setprio(1);
#pragma unroll
        for (int fm = 0; fm < 4; ++fm)
#pragma unroll
            for (int fn = 0; fn < 4; ++fn) {
                acch[fm][fn] = __builtin_amdgcn_mfma_i32_16x16x64_i8(ah[fm], bfr[fn], acch[fm][fn], 0, 0, 0);
                accl[fm][fn] = __builtin_amdgcn_mfma_i32_16x16x64_i8(al[fm], bfr[fn], accl[fm][fn], 0, 0, 0);
            }
        __builtin_amdgcn_s_setprio(0);
        cur ^= 1;
    }
#undef STG

    const int n0 = (jt & 7) * 128;
#pragma unroll
    for (int fm = 0; fm < 4; ++fm)
#pragma unroll
        for (int fn = 0; fn < 4; ++fn)
#pragma unroll
            for (int r = 0; r < 4; ++r) {
                int p = mt * 128 + wm * 64 + fm * 16 + kgl * 4 + r;
                int nl = wn * 64 + fn * 16 + lr;
                int vi = acch[fm][fn][r] * 256 + accl[fm][fn][r];
                float pre = (float)vi * 6.103515625e-05f;
                size_t idx = ((size_t)b * C_DIM + p) * NPIX + n0 + nl;
                out[idx] = (pre + bp[p]) * invp[p] + biasp[p] + x[idx];
            }
}

extern "C" void kernel_launch(void* const* d_in, const int* in_sizes, int n_in,
                              void* d_out, int out_size, void* d_ws, size_t ws_size,
                              hipStream_t stream) {
    const float* x  = (const float*)d_in[0];
    const float* wq = (const float*)d_in[1];
    const float* qg = (const float*)d_in[2];
    const float* qb = (const float*)d_in[3];
    const float* qm = (const float*)d_in[4];
    const float* qv = (const float*)d_in[5];
    const float* wk = (const float*)d_in[6];
    const float* kg = (const float*)d_in[7];
    const float* kb = (const float*)d_in[8];
    const float* km = (const float*)d_in[9];
    const float* kvv= (const float*)d_in[10];
    const float* wv = (const float*)d_in[11];
    const float* vg = (const float*)d_in[12];
    const float* vb = (const float*)d_in[13];
    const float* vm = (const float*)d_in[14];
    const float* vv = (const float*)d_in[15];
    const float* wp = (const float*)d_in[16];
    const float* bp = (const float*)d_in[17];
    const float* pg = (const float*)d_in[18];
    const float* pb = (const float*)d_in[19];
    const float* pm = (const float*)d_in[20];
    const float* pv = (const float*)d_in[21];

    const size_t SPIKE = (size_t)C_DIM * NTOT;       // bytes per spike blob
    char* sq  = (char*)d_ws;
    char* sk  = sq + SPIKE;
    char* sv  = sk + SPIKE;
    char* xs  = sv + SPIKE;
    char* wall = xs + SPIKE;                         // 4 sets x 2 planes
    unsigned char* maskb = (unsigned char*)(wall + (size_t)4 * 2 * PLANE_B);
    unsigned int* cntArr = (unsigned int*)(maskb + 16384);        // NBLK u32
    unsigned int* recsB  = cntArr + NBLK;                         // NBLK*BCAP u32
    float* invt  = (float*)(recsB + (size_t)NBLK * BCAP);
    float* biast = invt + 4 * C_DIM;
    char* wpb = wall + (size_t)3 * 2 * PLANE_B;

    prep_all<<<PREP_SPIKE_BLKS + PREP_W_BLKS + PREP_BN_BLKS, 256, 0, stream>>>(
        x, wq, wk, wv, wp,
        qg, qb, qm, qv, kg, kb, km, kvv, vg, vb, vm, vv, pg, pb, pm, pv,
        xs, wall, invt, biast);
    branch_mfma<<<dim3(JT_N, MT_N, 3), 256, 0, stream>>>(
        wall, xs, invt, biast, sq, cntArr, recsB);
    fixup<<<2048, 256, 0, stream>>>(xs, wq, wk, wv,
                                    qg, qb, qm, qv, kg, kb, km, kvv, vg, vb, vm, vv,
                                    sq, sk, sv, cntArr, recsB);
    kv_mask_blob<<<dim3(KT_N, B_DIM), 256, 0, stream>>>(sk, sv, maskb);
    final_mfma<<<dim3(JT_N, MT_N), 256, 0, stream>>>(
        wpb, sq, maskb, x, bp, invt, biast, (float*)d_out);
}

// Round 22
// 159.453 us; speedup vs baseline: 1.0188x; 1.0188x over previous
//
#include <hip/hip_runtime.h>
#include <cstdint>
#include <cstddef>

#define C_DIM 768
#define NPIX  1024
#define B_DIM 16
#define NTOT  16384
#define KT_N  12      // 768/64 K-tiles (K-step 64 for i8 MFMA)
#define MT_N  6       // 768/128 M-tiles in the A-blob layout
#define JT_N  128     // 16384/128 N-tiles
#define JT2_N 64      // 2 jt per block
#define MT2_N 12      // 768/64 M-tiles for the 64-row GEMM blocks
#define TAU   2.0e-3f
#define BCAP  64                       // record slots per block (expected ~7)
#define NBLK  (3 * MT2_N * JT2_N)      // 2304 branch blocks
#define PLANE_B (C_DIM * C_DIM)   // bytes per i8 weight plane
#define TILE_B  8192              // bytes per 128x64 i8 tile
// prep_all block ranges
#define PREP_SPIKE_BLKS (JT_N * KT_N)         // 1536
#define PREP_W_BLKS     576                   // 4*768*48 threads / 256
#define PREP_BN_BLKS    12

typedef __attribute__((ext_vector_type(4)))  int   int4v;
typedef __attribute__((ext_vector_type(16))) char  char16v;

__device__ __forceinline__ void gload16(const void* g, void* l) {
    __builtin_amdgcn_global_load_lds(
        (const __attribute__((address_space(1))) unsigned int*)g,
        (__attribute__((address_space(3))) unsigned int*)l, 16, 0, 0);
}

// ---------------------------------------------------------------------------
// Fused prep: [0,1536) spikes | [1536,2112) weights | [2112,2124) BN affine.
// ---------------------------------------------------------------------------
__global__ __launch_bounds__(256) void prep_all(
    const float* __restrict__ x,
    const float* __restrict__ w0, const float* __restrict__ w1,
    const float* __restrict__ w2, const float* __restrict__ w3,
    const float* __restrict__ qg, const float* __restrict__ qb,
    const float* __restrict__ qm, const float* __restrict__ qv,
    const float* __restrict__ kg, const float* __restrict__ kb,
    const float* __restrict__ km, const float* __restrict__ kv,
    const float* __restrict__ vg, const float* __restrict__ vb,
    const float* __restrict__ vm, const float* __restrict__ vv,
    const float* __restrict__ pg, const float* __restrict__ pb,
    const float* __restrict__ pm, const float* __restrict__ pv,
    char* __restrict__ xs, char* __restrict__ wall,
    float* __restrict__ invt, float* __restrict__ biast)
{
    const int blk = blockIdx.x;
    if (blk < PREP_SPIKE_BLKS) {
        const int jt = blk / KT_N, kt = blk - jt * KT_N;
        const int b  = jt >> 3;
        const int n0 = (jt & 7) * 128;
#pragma unroll
        for (int i = 0; i < 2; ++i) {
            int q = threadIdx.x + i * 256;    // (kg, col)
            int kgc = q >> 7, col = q & 127;
            char16v sv;
#pragma unroll
            for (int e = 0; e < 16; ++e) {
                float xv = x[((size_t)b * C_DIM + (kt * 64 + kgc * 16 + e)) * NPIX + n0 + col];
                sv[e] = (xv >= 2.0f) ? (char)1 : (char)0;
            }
            *(char16v*)(xs + (size_t)(jt * KT_N + kt) * TILE_B + (size_t)q * 16) = sv;
        }
    } else if (blk < PREP_SPIKE_BLKS + PREP_W_BLKS) {
        int t = (blk - PREP_SPIKE_BLKS) * 256 + threadIdx.x;  // 0..147455
        int set = t / (C_DIM * 48);
        int rem = t - set * (C_DIM * 48);
        int o = rem / 48, c16 = rem - (rem / 48) * 48;        // row, 16-col chunk
        const float* w = set == 0 ? w0 : set == 1 ? w1 : set == 2 ? w2 : w3;
        char* pl = wall + (size_t)set * 2 * PLANE_B;
        char16v H, L;
#pragma unroll
        for (int e = 0; e < 16; ++e) {
            float wv = w[(size_t)o * C_DIM + c16 * 16 + e];   // coalesced 64B/thread
            int w16 = (int)lrintf(wv * 16384.0f);
            w16 = w16 > 32639 ? 32639 : (w16 < -32639 ? -32639 : w16);
            int hi = (w16 + 128) >> 8;
            int lo = w16 - (hi << 8);
            H[e] = (char)hi;
            L[e] = (char)lo;
        }
        int mt = o >> 7, m = o & 127;
        int kt = c16 >> 2, kgc = c16 & 3;
        size_t base = (size_t)(kt * MT_N + mt) * TILE_B + kgc * 2048 + (size_t)m * 16;
        *(char16v*)(pl + base)           = H;
        *(char16v*)(pl + PLANE_B + base) = L;
    } else {
        int i = (blk - PREP_SPIKE_BLKS - PREP_W_BLKS) * 256 + threadIdx.x;  // 0..3071
        if (i >= 4 * C_DIM) return;
        int set = i / C_DIM, o = i - set * C_DIM;
        const float* g = set == 0 ? qg : set == 1 ? kg : set == 2 ? vg : pg;
        const float* b = set == 0 ? qb : set == 1 ? kb : set == 2 ? vb : pb;
        const float* m = set == 0 ? qm : set == 1 ? km : set == 2 ? vm : pm;
        const float* v = set == 0 ? qv : set == 1 ? kv : set == 2 ? vv : pv;
        float inv = g[o] / sqrtf(v[o] + 1e-5f);
        invt[i]  = inv;
        biast[i] = b[o] - m[o] * inv;
    }
}

// ---------------------------------------------------------------------------
// Branch GEMMs (q,k,v via blockIdx.z), 512 thr = 8 waves (2M x 4N),
// wave 32x64, block 64x256 (2 jt). mt is the FASTEST grid dim so
// consecutively-dispatched blocks share the jt2 B-panels (L2 locality).
// A+B in LDS (24KB/stage, 2 stages), counted-vmcnt pipeline: vmcnt(3)
// never 0 mid-loop, 2 raw barriers/iter, lgkm fence + sched_barrier.
// Band records -> per-block regions via LDS counter (no global atomics).
// ---------------------------------------------------------------------------
__global__ __launch_bounds__(512, 4) void branch_mfma(
    const char* __restrict__ wall, const char* __restrict__ xsblob,
    const float* __restrict__ invt, const float* __restrict__ biast,
    char* __restrict__ sall,
    unsigned int* __restrict__ cntArr, unsigned int* __restrict__ recsB)
{
    __shared__ char stage[2][24576];   // [A_hi 4K][A_lo 4K][B0 8K][B1 8K]
    __shared__ unsigned int lcnt;
    const int mt = blockIdx.x, jt2 = blockIdx.y, z = blockIdx.z;  // mt fastest
    const int jt0 = jt2 * 2;
    const int tid = threadIdx.x;
    const int lane = tid & 63, wid = tid >> 6;
    const int wm = wid >> 2, wn = wid & 3;       // 2(M) x 4(N) waves, 32x64 each
    const int lr = lane & 15, kgl = lane >> 4;
    const char* wblob = wall + (size_t)z * 2 * PLANE_B;
    char* sblob = sall + (size_t)z * (size_t)C_DIM * NTOT;
    const float* invz  = invt  + z * C_DIM;
    const float* biasz = biast + z * C_DIM;
    const unsigned int blk = ((unsigned)z * MT2_N + mt) * JT2_N + jt2;

    const int mt128 = mt >> 1, mrow = (mt & 1) * 64;
    const int aIdx = tid & 255;
    const size_t aoff_src = (size_t)((tid < 256) ? 0 : PLANE_B)
                          + (aIdx >> 6) * 2048 + (size_t)(mrow + (aIdx & 63)) * 16;

#define STG(buf, ktA) do {                                                     \
        const char* Ab_ = wblob + (size_t)((ktA) * MT_N + mt128) * TILE_B;     \
        const char* B0_ = xsblob + (size_t)(jt0 * KT_N + (ktA)) * TILE_B;      \
        const char* B1_ = xsblob + (size_t)((jt0 + 1) * KT_N + (ktA)) * TILE_B;\
        char* d_ = stage[buf];                                                 \
        gload16(Ab_ + aoff_src,                d_ + tid * 16);                 \
        gload16(B0_ + (size_t)tid * 16,        d_ + 8192 + tid * 16);          \
        gload16(B1_ + (size_t)tid * 16,        d_ + 16384 + tid * 16);         \
    } while (0)

    int4v acch[2][4], accl[2][4];
#pragma unroll
    for (int a = 0; a < 2; ++a)
#pragma unroll
        for (int b2 = 0; b2 < 4; ++b2) {
            acch[a][b2] = (int4v){0, 0, 0, 0};
            accl[a][b2] = (int4v){0, 0, 0, 0};
        }

    STG(0, 0);
    STG(1, 1);
    if (tid == 0) lcnt = 0;
    int cur = 0;
    const int arow = (wm * 32 + lr) * 16;        // fm=0; fm=1 at +256
    const int bbase = 8192 + (wn >> 1) * 8192 + ((wn & 1) * 64) * 16;
    for (int kt = 0; kt < KT_N; ++kt) {
        if (kt + 1 < KT_N) asm volatile("s_waitcnt vmcnt(3)");
        else               asm volatile("s_waitcnt vmcnt(0)");
        __builtin_amdgcn_s_barrier();            // stage(kt) visible
        __builtin_amdgcn_sched_barrier(0);
        const char* st = stage[cur];
        int4v ah0 = *(const int4v*)&st[kgl * 1024 + arow];
        int4v ah1 = *(const int4v*)&st[kgl * 1024 + arow + 256];
        int4v al0 = *(const int4v*)&st[4096 + kgl * 1024 + arow];
        int4v al1 = *(const int4v*)&st[4096 + kgl * 1024 + arow + 256];
        int4v bfr[4];
#pragma unroll
        for (int fn = 0; fn < 4; ++fn)
            bfr[fn] = *(const int4v*)&st[bbase + kgl * 2048 + (fn * 16 + lr) * 16];
        __builtin_amdgcn_sched_barrier(0);
        asm volatile("s_waitcnt lgkmcnt(0)");
        __builtin_amdgcn_sched_barrier(0);
        __builtin_amdgcn_s_barrier();            // all waves done reading buf
        if (kt + 2 < KT_N) STG(cur, kt + 2);     // overwrite safe
        __builtin_amdgcn_s_setprio(1);
#pragma unroll
        for (int fn = 0; fn < 4; ++fn) {
            acch[0][fn] = __builtin_amdgcn_mfma_i32_16x16x64_i8(ah0, bfr[fn], acch[0][fn], 0, 0, 0);
            acch[1][fn] = __builtin_amdgcn_mfma_i32_16x16x64_i8(ah1, bfr[fn], acch[1][fn], 0, 0, 0);
            accl[0][fn] = __builtin_amdgcn_mfma_i32_16x16x64_i8(al0, bfr[fn], accl[0][fn], 0, 0, 0);
            accl[1][fn] = __builtin_amdgcn_mfma_i32_16x16x64_i8(al1, bfr[fn], accl[1][fn], 0, 0, 0);
        }
        __builtin_amdgcn_s_setprio(0);
        cur ^= 1;
    }
#undef STG

    // ---- epilogue: BN + spike in registers; band records -> per-block region
    const int jtw = jt0 + (wn >> 1);             // this wave's jt
    const int colb = (wn & 1) * 64;
    unsigned int pk[2][4];
#pragma unroll
    for (int fm = 0; fm < 2; ++fm)
#pragma unroll
        for (int fn = 0; fn < 4; ++fn) {
            unsigned int p = 0;
#pragma unroll
            for (int r = 0; r < 4; ++r) {
                int o = mt * 64 + wm * 32 + fm * 16 + kgl * 4 + r;
                int vi = acch[fm][fn][r] * 256 + accl[fm][fn][r];
                float y = (float)vi * 6.103515625e-05f;    // *2^-14, exact
                float ybn = y * invz[o] + biasz[o];
                if (ybn >= 2.0f) p |= (1u << (r * 8));
                if (fabsf(ybn - 2.0f) < TAU) {
                    unsigned int idx = atomicAdd(&lcnt, 1u);   // LDS atomic
                    if (idx < BCAP) {
                        int j = jtw * 128 + colb + fn * 16 + lr;
                        recsB[(size_t)blk * BCAP + idx] =
                            ((unsigned)z << 24) | ((unsigned)o << 14) | (unsigned)j;
                    }
                }
            }
            pk[fm][fn] = p;
        }

    // shfl-transpose pack -> direct blob stores
#pragma unroll
    for (int fnPair = 0; fnPair < 2; ++fnPair) {
        unsigned int got[4];
#pragma unroll
        for (int t = 0; t < 4; ++t) {
            int sel = (kgl + t) & 3;
            int sfm = sel >> 1, sfn = (sel & 1) * 2 + fnPair;
            unsigned int send =
                sfm == 0 ? (sfn == 0 ? pk[0][0] : sfn == 1 ? pk[0][1] : sfn == 2 ? pk[0][2] : pk[0][3])
                         : (sfn == 0 ? pk[1][0] : sfn == 1 ? pk[1][1] : sfn == 2 ? pk[1][2] : pk[1][3]);
            int src = (((kgl - t) & 3) << 4) + lr;
            got[t] = (unsigned int)__shfl((int)send, src);
        }
        unsigned int part[4];
#pragma unroll
        for (int j = 0; j < 4; ++j) {
            int tsel = (kgl - j) & 3;
            part[j] = tsel == 0 ? got[0] : tsel == 1 ? got[1]
                    : tsel == 2 ? got[2] : got[3];
        }
        int4v chunk = (int4v){(int)part[0], (int)part[1], (int)part[2], (int)part[3]};
        int kg2 = wm * 2 + (kgl >> 1);
        int col = colb + ((kgl & 1) * 2 + fnPair) * 16 + lr;
        size_t off = (size_t)(jtw * KT_N + mt) * TILE_B + (size_t)kg2 * 2048 + (size_t)col * 16;
        *(int4v*)(sblob + off) = chunk;
    }
    __syncthreads();
    if (tid == 0) {
        unsigned int c = lcnt;
        cntArr[blk] = c > BCAP ? BCAP : c;
    }
}

// ---------------------------------------------------------------------------
// Pass-2 fixup over per-block record regions, SLOT-MAJOR pair distribution
// (slot = p / NBLK). Bit-exact numpy fp32 re-resolution (skip-zero exact).
// ---------------------------------------------------------------------------
__global__ __launch_bounds__(256) void fixup(
    const char* __restrict__ xs,
    const float* __restrict__ wq, const float* __restrict__ wk, const float* __restrict__ wv,
    const float* __restrict__ qg, const float* __restrict__ qb, const float* __restrict__ qm, const float* __restrict__ qv,
    const float* __restrict__ kg, const float* __restrict__ kb2, const float* __restrict__ km, const float* __restrict__ kvr,
    const float* __restrict__ vg, const float* __restrict__ vb, const float* __restrict__ vm, const float* __restrict__ vv,
    char* __restrict__ sq, char* __restrict__ sk, char* __restrict__ sv,
    const unsigned int* __restrict__ cntArr, const unsigned int* __restrict__ recsB)
{
#pragma clang fp contract(off)
    __shared__ float cw[4][C_DIM];
    const int lane = threadIdx.x & 63;
    const int wvid = threadIdx.x >> 6;
    const int gwave = blockIdx.x * 4 + wvid;
    const int nwaves = gridDim.x * 4;
    const int npairs = NBLK * BCAP;

    for (int p = gwave; p < npairs; p += nwaves) {
        int slot = p / NBLK;            // slow index: populated slots first
        int reg  = p - slot * NBLK;
        if ((unsigned)slot >= cntArr[reg]) continue;
        unsigned int rec = recsB[(size_t)reg * BCAP + slot];
        int plane = rec >> 24, o = (rec >> 14) & 1023, j = rec & 16383;
        int jt = j >> 7, col = j & 127;
        const float* w = plane == 0 ? wq : plane == 1 ? wk : wv;
        int base = 0;
#pragma unroll
        for (int cc = 0; cc < 12; ++cc) {
            int c = cc * 64 + lane;
            char s = xs[(size_t)(jt * KT_N + (c >> 6)) * TILE_B
                        + ((c >> 4) & 3) * 2048 + col * 16 + (c & 15)];
            float wvv = w[(size_t)o * C_DIM + c];
            bool act = (s != 0);
            unsigned long long m = __ballot(act);
            int pos = __popcll(m & ((1ull << lane) - 1ull));
            if (act) cw[wvid][base + pos] = wvv;
            base += __popcll(m);
        }
        __builtin_amdgcn_s_waitcnt(0);       // wave-coherent LDS
        if (lane == 0) {
            float s = 0.0f;
            for (int i = 0; i < base; ++i) s = s + cw[wvid][i];   // strict order
            const float* g  = plane == 0 ? qg : plane == 1 ? kg : vg;
            const float* be = plane == 0 ? qb : plane == 1 ? kb2 : vb;
            const float* me = plane == 0 ? qm : plane == 1 ? km : vm;
            const float* va = plane == 0 ? qv : plane == 1 ? kvr : vv;
            float invv = g[o] / sqrtf(va[o] + 1e-5f);
            float t1 = me[o] * invv;
            float bias = be[o] - t1;
            float t3 = s * invv;
            float ybn = t3 + bias;
            char spv = (ybn >= 2.0f) ? (char)1 : (char)0;
            char* blob = plane == 0 ? sq : plane == 1 ? sk : sv;
            blob[(size_t)(jt * KT_N + (o >> 6)) * TILE_B
                 + ((o >> 4) & 3) * 2048 + col * 16 + (o & 15)] = spv;
        }
    }
}

// ---------------------------------------------------------------------------
// maskb[b][c] = OR_n (sk & sv), bytes {0,1}
// ---------------------------------------------------------------------------
__global__ __launch_bounds__(256) void kv_mask_blob(
    const char* __restrict__ sk, const char* __restrict__ sv,
    unsigned char* __restrict__ maskb)
{
    const int kt = blockIdx.x, b = blockIdx.y;
    const int t = threadIdx.x;
    const int kgc = t >> 6;
    const int col0 = (t & 63) * 2;
    __shared__ unsigned int lmask[4][4];
    if (t < 16) lmask[t >> 2][t & 3] = 0;
    __syncthreads();
    uint4 acc = make_uint4(0, 0, 0, 0);
    for (int jti = 0; jti < 8; ++jti) {
        size_t base = (size_t)((b * 8 + jti) * KT_N + kt) * TILE_B + kgc * 2048;
#pragma unroll
        for (int cc = 0; cc < 2; ++cc) {
            uint4 kk = *(const uint4*)(sk + base + (size_t)(col0 + cc) * 16);
            uint4 vv = *(const uint4*)(sv + base + (size_t)(col0 + cc) * 16);
            acc.x |= (kk.x & vv.x); acc.y |= (kk.y & vv.y);
            acc.z |= (kk.z & vv.z); acc.w |= (kk.w & vv.w);
        }
    }
    if (acc.x) atomicOr(&lmask[kgc][0], acc.x);
    if (acc.y) atomicOr(&lmask[kgc][1], acc.y);
    if (acc.z) atomicOr(&lmask[kgc][2], acc.z);
    if (acc.w) atomicOr(&lmask[kgc][3], acc.w);
    __syncthreads();
    if (t < 64) {
        int kg2 = t >> 4, e = t & 15;
        unsigned int dw = lmask[kg2][e >> 2];
        unsigned char byte = (dw >> ((e & 3) * 8)) & 0xFF;
        maskb[(size_t)b * C_DIM + kt * 64 + t] = byte ? 1 : 0;
    }
}

// ---------------------------------------------------------------------------
// Final projection: out = (wp·(sq & mask) + bp)*inv + bias + x
// Same 64x256 counted-vmcnt pipeline (mt fastest grid dim); mask in LDS.
// ---------------------------------------------------------------------------
__global__ __launch_bounds__(512, 4) void final_mfma(
    const char* __restrict__ wblob, const char* __restrict__ sqblob,
    const unsigned char* __restrict__ maskb,
    const float* __restrict__ x, const float* __restrict__ bp,
    const float* __restrict__ invt, const float* __restrict__ biast,
    float* __restrict__ out)
{
    __shared__ char stage[2][24576];
    __shared__ char mlds[768];
    const int mt = blockIdx.x, jt2 = blockIdx.y;   // mt fastest
    const int jt0 = jt2 * 2;
    const int tid = threadIdx.x;
    const int lane = tid & 63, wid = tid >> 6;
    const int wm = wid >> 2, wn = wid & 3;
    const int lr = lane & 15, kgl = lane >> 4;
    const int b = jt0 >> 3;
    const float* invp  = invt  + 3 * C_DIM;
    const float* biasp = biast + 3 * C_DIM;

    const int mt128 = mt >> 1, mrow = (mt & 1) * 64;
    const int aIdx = tid & 255;
    const size_t aoff_src = (size_t)((tid < 256) ? 0 : PLANE_B)
                          + (aIdx >> 6) * 2048 + (size_t)(mrow + (aIdx & 63)) * 16;

#define STG(buf, ktA) do {                                                     \
        const char* Ab_ = wblob + (size_t)((ktA) * MT_N + mt128) * TILE_B;     \
        const char* B0_ = sqblob + (size_t)(jt0 * KT_N + (ktA)) * TILE_B;      \
        const char* B1_ = sqblob + (size_t)((jt0 + 1) * KT_N + (ktA)) * TILE_B;\
        char* d_ = stage[buf];                                                 \
        gload16(Ab_ + aoff_src,                d_ + tid * 16);                 \
        gload16(B0_ + (size_t)tid * 16,        d_ + 8192 + tid * 16);          \
        gload16(B1_ + (size_t)tid * 16,        d_ + 16384 + tid * 16);         \
    } while (0)

    int4v acch[2][4], accl[2][4];
#pragma unroll
    for (int a = 0; a < 2; ++a)
#pragma unroll
        for (int b2 = 0; b2 < 4; ++b2) {
            acch[a][b2] = (int4v){0, 0, 0, 0};
            accl[a][b2] = (int4v){0, 0, 0, 0};
        }

    if (tid < 48)
        *(int4v*)&mlds[tid * 16] = *(const int4v*)(maskb + (size_t)b * C_DIM + tid * 16);
    STG(0, 0);
    STG(1, 1);
    __syncthreads();                 // one-time full drain (mlds + stages 0,1)
    int cur = 0;
    const int arow = (wm * 32 + lr) * 16;
    const int bbase = 8192 + (wn >> 1) * 8192 + ((wn & 1) * 64) * 16;
    for (int kt = 0; kt < KT_N; ++kt) {
        if (kt + 1 < KT_N) asm volatile("s_waitcnt vmcnt(3)");
        else               asm volatile("s_waitcnt vmcnt(0)");
        __builtin_amdgcn_s_barrier();
        __builtin_amdgcn_sched_barrier(0);
        const char* st = stage[cur];
        int4v ah0 = *(const int4v*)&st[kgl * 1024 + arow];
        int4v ah1 = *(const int4v*)&st[kgl * 1024 + arow + 256];
        int4v al0 = *(const int4v*)&st[4096 + kgl * 1024 + arow];
        int4v al1 = *(const int4v*)&st[4096 + kgl * 1024 + arow + 256];
        int4v mp = *(const int4v*)&mlds[kt * 64 + kgl * 16];
        int4v bfr[4];
#pragma unroll
        for (int fn = 0; fn < 4; ++fn)
            bfr[fn] = *(const int4v*)&st[bbase + kgl * 2048 + (fn * 16 + lr) * 16];
        __builtin_amdgcn_sched_barrier(0);
        asm volatile("s_waitcnt lgkmcnt(0)");
        __builtin_amdgcn_sched_barrier(0);
        __builtin_amdgcn_s_barrier();
        if (kt + 2 < KT_N) STG(cur, kt + 2);
#pragma unroll
        for (int fn = 0; fn < 4; ++fn) bfr[fn] &= mp;
        __builtin_amdgcn_s_setprio(1);
#pragma unroll
        for (int fn = 0; fn < 4; ++fn) {
            acch[0][fn] = __builtin_amdgcn_mfma_i32_16x16x64_i8(ah0, bfr[fn], acch[0][fn], 0, 0, 0);
            acch[1][fn] = __builtin_amdgcn_mfma_i32_16x16x64_i8(ah1, bfr[fn], acch[1][fn], 0, 0, 0);
            accl[0][fn] = __builtin_amdgcn_mfma_i32_16x16x64_i8(al0, bfr[fn], accl[0][fn], 0, 0, 0);
            accl[1][fn] = __builtin_amdgcn_mfma_i32_16x16x64_i8(al1, bfr[fn], accl[1][fn], 0, 0, 0);
        }
        __builtin_amdgcn_s_setprio(0);
        cur ^= 1;
    }
#undef STG

    const int jtw = jt0 + (wn >> 1);
    const int n0 = (jtw & 7) * 128;
    const int colb = (wn & 1) * 64;
#pragma unroll
    for (int fm = 0; fm < 2; ++fm)
#pragma unroll
        for (int fn = 0; fn < 4; ++fn)
#pragma unroll
            for (int r = 0; r < 4; ++r) {
                int p = mt * 64 + wm * 32 + fm * 16 + kgl * 4 + r;
                int nl = colb + fn * 16 + lr;
                int vi = acch[fm][fn][r] * 256 + accl[fm][fn][r];
                float pre = (float)vi * 6.103515625e-05f;
                size_t idx = ((size_t)b * C_DIM + p) * NPIX + n0 + nl;
                out[idx] = (pre + bp[p]) * invp[p] + biasp[p] + x[idx];
            }
}

extern "C" void kernel_launch(void* const* d_in, const int* in_sizes, int n_in,
                              void* d_out, int out_size, void* d_ws, size_t ws_size,
                              hipStream_t stream) {
    const float* x  = (const float*)d_in[0];
    const float* wq = (const float*)d_in[1];
    const float* qg = (const float*)d_in[2];
    const float* qb = (const float*)d_in[3];
    const float* qm = (const float*)d_in[4];
    const float* qv = (const float*)d_in[5];
    const float* wk = (const float*)d_in[6];
    const float* kg = (const float*)d_in[7];
    const float* kb = (const float*)d_in[8];
    const float* km = (const float*)d_in[9];
    const float* kvv= (const float*)d_in[10];
    const float* wv = (const float*)d_in[11];
    const float* vg = (const float*)d_in[12];
    const float* vb = (const float*)d_in[13];
    const float* vm = (const float*)d_in[14];
    const float* vv = (const float*)d_in[15];
    const float* wp = (const float*)d_in[16];
    const float* bp = (const float*)d_in[17];
    const float* pg = (const float*)d_in[18];
    const float* pb = (const float*)d_in[19];
    const float* pm = (const float*)d_in[20];
    const float* pv = (const float*)d_in[21];

    const size_t SPIKE = (size_t)C_DIM * NTOT;       // bytes per spike blob
    char* sq  = (char*)d_ws;
    char* sk  = sq + SPIKE;
    char* sv  = sk + SPIKE;
    char* xs  = sv + SPIKE;
    char* wall = xs + SPIKE;                         // 4 sets x 2 planes
    unsigned char* maskb = (unsigned char*)(wall + (size_t)4 * 2 * PLANE_B);
    unsigned int* cntArr = (unsigned int*)(maskb + 16384);        // NBLK u32
    unsigned int* recsB  = cntArr + NBLK;                         // NBLK*BCAP u32
    float* invt  = (float*)(recsB + (size_t)NBLK * BCAP);
    float* biast = invt + 4 * C_DIM;
    char* wpb = wall + (size_t)3 * 2 * PLANE_B;

    prep_all<<<PREP_SPIKE_BLKS + PREP_W_BLKS + PREP_BN_BLKS, 256, 0, stream>>>(
        x, wq, wk, wv, wp,
        qg, qb, qm, qv, kg, kb, km, kvv, vg, vb, vm, vv, pg, pb, pm, pv,
        xs, wall, invt, biast);
    branch_mfma<<<dim3(MT2_N, JT2_N, 3), 512, 0, stream>>>(
        wall, xs, invt, biast, sq, cntArr, recsB);
    fixup<<<2048, 256, 0, stream>>>(xs, wq, wk, wv,
                                    qg, qb, qm, qv, kg, kb, km, kvv, vg, vb, vm, vv,
                                    sq, sk, sv, cntArr, recsB);
    kv_mask_blob<<<dim3(KT_N, B_DIM), 256, 0, stream>>>(sk, sv, maskb);
    final_mfma<<<dim3(MT2_N, JT2_N), 512, 0, stream>>>(
        wpb, sq, maskb, x, bp, invt, biast, (float*)d_out);
}

// Round 23
// 148.481 us; speedup vs baseline: 1.0941x; 1.0739x over previous
//
#include <hip/hip_runtime.h>
#include <cstdint>
#include <cstddef>

#define C_DIM 768
#define NPIX  1024
#define B_DIM 16
#define NTOT  16384
#define KT_N  12      // 768/64 K-tiles (K-step 64 for i8 MFMA)
#define MT_N  6       // 768/128 M-tiles in the A-blob layout
#define JT_N  128     // 16384/128 N-tiles
#define JT2_N 64      // 2 jt per block
#define MT2_N 12      // 768/64 M-tiles for the 64-row GEMM blocks
#define TAU   2.0e-3f
#define BCAP  64                       // record slots per block (expected ~7)
#define NBLK  (3 * MT2_N * JT2_N)      // 2304 branch blocks
#define PLANE_B (C_DIM * C_DIM)   // bytes per i8 weight plane
#define TILE_B  8192              // bytes per 128x64 i8 tile
// prep_all block ranges
#define PREP_SPIKE_BLKS (JT_N * KT_N)         // 1536
#define PREP_W_BLKS     576                   // 4*768*48 threads / 256
#define PREP_BN_BLKS    12

typedef __attribute__((ext_vector_type(4)))  int   int4v;
typedef __attribute__((ext_vector_type(16))) char  char16v;

__device__ __forceinline__ void gload16(const void* g, void* l) {
    __builtin_amdgcn_global_load_lds(
        (const __attribute__((address_space(1))) unsigned int*)g,
        (__attribute__((address_space(3))) unsigned int*)l, 16, 0, 0);
}

// ---------------------------------------------------------------------------
// Fused prep: [0,1536) spikes | [1536,2112) weights | [2112,2124) BN affine.
// ---------------------------------------------------------------------------
__global__ __launch_bounds__(256) void prep_all(
    const float* __restrict__ x,
    const float* __restrict__ w0, const float* __restrict__ w1,
    const float* __restrict__ w2, const float* __restrict__ w3,
    const float* __restrict__ qg, const float* __restrict__ qb,
    const float* __restrict__ qm, const float* __restrict__ qv,
    const float* __restrict__ kg, const float* __restrict__ kb,
    const float* __restrict__ km, const float* __restrict__ kv,
    const float* __restrict__ vg, const float* __restrict__ vb,
    const float* __restrict__ vm, const float* __restrict__ vv,
    const float* __restrict__ pg, const float* __restrict__ pb,
    const float* __restrict__ pm, const float* __restrict__ pv,
    char* __restrict__ xs, char* __restrict__ wall,
    float* __restrict__ invt, float* __restrict__ biast)
{
    const int blk = blockIdx.x;
    if (blk < PREP_SPIKE_BLKS) {
        const int jt = blk / KT_N, kt = blk - jt * KT_N;
        const int b  = jt >> 3;
        const int n0 = (jt & 7) * 128;
#pragma unroll
        for (int i = 0; i < 2; ++i) {
            int q = threadIdx.x + i * 256;    // (kg, col)
            int kgc = q >> 7, col = q & 127;
            char16v sv;
#pragma unroll
            for (int e = 0; e < 16; ++e) {
                float xv = x[((size_t)b * C_DIM + (kt * 64 + kgc * 16 + e)) * NPIX + n0 + col];
                sv[e] = (xv >= 2.0f) ? (char)1 : (char)0;
            }
            *(char16v*)(xs + (size_t)(jt * KT_N + kt) * TILE_B + (size_t)q * 16) = sv;
        }
    } else if (blk < PREP_SPIKE_BLKS + PREP_W_BLKS) {
        int t = (blk - PREP_SPIKE_BLKS) * 256 + threadIdx.x;  // 0..147455
        int set = t / (C_DIM * 48);
        int rem = t - set * (C_DIM * 48);
        int o = rem / 48, c16 = rem - (rem / 48) * 48;        // row, 16-col chunk
        const float* w = set == 0 ? w0 : set == 1 ? w1 : set == 2 ? w2 : w3;
        char* pl = wall + (size_t)set * 2 * PLANE_B;
        char16v H, L;
#pragma unroll
        for (int e = 0; e < 16; ++e) {
            float wv = w[(size_t)o * C_DIM + c16 * 16 + e];   // coalesced 64B/thread
            int w16 = (int)lrintf(wv * 16384.0f);
            w16 = w16 > 32639 ? 32639 : (w16 < -32639 ? -32639 : w16);
            int hi = (w16 + 128) >> 8;
            int lo = w16 - (hi << 8);
            H[e] = (char)hi;
            L[e] = (char)lo;
        }
        int mt = o >> 7, m = o & 127;
        int kt = c16 >> 2, kgc = c16 & 3;
        size_t base = (size_t)(kt * MT_N + mt) * TILE_B + kgc * 2048 + (size_t)m * 16;
        *(char16v*)(pl + base)           = H;
        *(char16v*)(pl + PLANE_B + base) = L;
    } else {
        int i = (blk - PREP_SPIKE_BLKS - PREP_W_BLKS) * 256 + threadIdx.x;  // 0..3071
        if (i >= 4 * C_DIM) return;
        int set = i / C_DIM, o = i - set * C_DIM;
        const float* g = set == 0 ? qg : set == 1 ? kg : set == 2 ? vg : pg;
        const float* b = set == 0 ? qb : set == 1 ? kb : set == 2 ? vb : pb;
        const float* m = set == 0 ? qm : set == 1 ? km : set == 2 ? vm : pm;
        const float* v = set == 0 ? qv : set == 1 ? kv : set == 2 ? vv : pv;
        float inv = g[o] / sqrtf(v[o] + 1e-5f);
        invt[i]  = inv;
        biast[i] = b[o] - m[o] * inv;
    }
}

// ---------------------------------------------------------------------------
// Branch GEMMs (q,k,v via blockIdx.z), 512 thr = 8 waves (2M x 4N),
// wave 32x64, block 64x256 (2 jt). A+B in LDS (24KB/stage, 2 stages),
// counted-vmcnt pipeline: vmcnt(3) never 0 mid-loop, 2 raw barriers/iter,
// lgkm fence + sched_barrier. Band records -> per-block regions via LDS
// counter (no global atomics). Epilogue: in-register BN+spike+shfl-pack.
// ---------------------------------------------------------------------------
__global__ __launch_bounds__(512, 4) void branch_mfma(
    const char* __restrict__ wall, const char* __restrict__ xsblob,
    const float* __restrict__ invt, const float* __restrict__ biast,
    char* __restrict__ sall,
    unsigned int* __restrict__ cntArr, unsigned int* __restrict__ recsB)
{
    __shared__ char stage[2][24576];   // [A_hi 4K][A_lo 4K][B0 8K][B1 8K]
    __shared__ unsigned int lcnt;
    const int jt2 = blockIdx.x, mt = blockIdx.y, z = blockIdx.z;
    const int jt0 = jt2 * 2;
    const int tid = threadIdx.x;
    const int lane = tid & 63, wid = tid >> 6;
    const int wm = wid >> 2, wn = wid & 3;       // 2(M) x 4(N) waves, 32x64 each
    const int lr = lane & 15, kgl = lane >> 4;
    const char* wblob = wall + (size_t)z * 2 * PLANE_B;
    char* sblob = sall + (size_t)z * (size_t)C_DIM * NTOT;
    const float* invz  = invt  + z * C_DIM;
    const float* biasz = biast + z * C_DIM;
    const unsigned int blk = ((unsigned)z * MT2_N + mt) * JT2_N + jt2;

    const int mt128 = mt >> 1, mrow = (mt & 1) * 64;
    const int aIdx = tid & 255;
    const size_t aoff_src = (size_t)((tid < 256) ? 0 : PLANE_B)
                          + (aIdx >> 6) * 2048 + (size_t)(mrow + (aIdx & 63)) * 16;

#define STG(buf, ktA) do {                                                     \
        const char* Ab_ = wblob + (size_t)((ktA) * MT_N + mt128) * TILE_B;     \
        const char* B0_ = xsblob + (size_t)(jt0 * KT_N + (ktA)) * TILE_B;      \
        const char* B1_ = xsblob + (size_t)((jt0 + 1) * KT_N + (ktA)) * TILE_B;\
        char* d_ = stage[buf];                                                 \
        gload16(Ab_ + aoff_src,                d_ + tid * 16);                 \
        gload16(B0_ + (size_t)tid * 16,        d_ + 8192 + tid * 16);          \
        gload16(B1_ + (size_t)tid * 16,        d_ + 16384 + tid * 16);         \
    } while (0)

    int4v acch[2][4], accl[2][4];
#pragma unroll
    for (int a = 0; a < 2; ++a)
#pragma unroll
        for (int b2 = 0; b2 < 4; ++b2) {
            acch[a][b2] = (int4v){0, 0, 0, 0};
            accl[a][b2] = (int4v){0, 0, 0, 0};
        }

    STG(0, 0);
    STG(1, 1);
    if (tid == 0) lcnt = 0;
    int cur = 0;
    const int arow = (wm * 32 + lr) * 16;        // fm=0; fm=1 at +256
    const int bbase = 8192 + (wn >> 1) * 8192 + ((wn & 1) * 64) * 16;
    for (int kt = 0; kt < KT_N; ++kt) {
        if (kt + 1 < KT_N) asm volatile("s_waitcnt vmcnt(3)");
        else               asm volatile("s_waitcnt vmcnt(0)");
        __builtin_amdgcn_s_barrier();            // stage(kt) visible
        __builtin_amdgcn_sched_barrier(0);
        const char* st = stage[cur];
        int4v ah0 = *(const int4v*)&st[kgl * 1024 + arow];
        int4v ah1 = *(const int4v*)&st[kgl * 1024 + arow + 256];
        int4v al0 = *(const int4v*)&st[4096 + kgl * 1024 + arow];
        int4v al1 = *(const int4v*)&st[4096 + kgl * 1024 + arow + 256];
        int4v bfr[4];
#pragma unroll
        for (int fn = 0; fn < 4; ++fn)
            bfr[fn] = *(const int4v*)&st[bbase + kgl * 2048 + (fn * 16 + lr) * 16];
        __builtin_amdgcn_sched_barrier(0);
        asm volatile("s_waitcnt lgkmcnt(0)");
        __builtin_amdgcn_sched_barrier(0);
        __builtin_amdgcn_s_barrier();            // all waves done reading buf
        if (kt + 2 < KT_N) STG(cur, kt + 2);     // overwrite safe
        __builtin_amdgcn_s_setprio(1);
#pragma unroll
        for (int fn = 0; fn < 4; ++fn) {
            acch[0][fn] = __builtin_amdgcn_mfma_i32_16x16x64_i8(ah0, bfr[fn], acch[0][fn], 0, 0, 0);
            acch[1][fn] = __builtin_amdgcn_mfma_i32_16x16x64_i8(ah1, bfr[fn], acch[1][fn], 0, 0, 0);
            accl[0][fn] = __builtin_amdgcn_mfma_i32_16x16x64_i8(al0, bfr[fn], accl[0][fn], 0, 0, 0);
            accl[1][fn] = __builtin_amdgcn_mfma_i32_16x16x64_i8(al1, bfr[fn], accl[1][fn], 0, 0, 0);
        }
        __builtin_amdgcn_s_setprio(0);
        cur ^= 1;
    }
#undef STG

    // ---- epilogue: BN + spike in registers; band records -> per-block region
    const int jtw = jt0 + (wn >> 1);             // this wave's jt
    const int colb = (wn & 1) * 64;
    unsigned int pk[2][4];
#pragma unroll
    for (int fm = 0; fm < 2; ++fm)
#pragma unroll
        for (int fn = 0; fn < 4; ++fn) {
            unsigned int p = 0;
#pragma unroll
            for (int r = 0; r < 4; ++r) {
                int o = mt * 64 + wm * 32 + fm * 16 + kgl * 4 + r;
                int vi = acch[fm][fn][r] * 256 + accl[fm][fn][r];
                float y = (float)vi * 6.103515625e-05f;    // *2^-14, exact
                float ybn = y * invz[o] + biasz[o];
                if (ybn >= 2.0f) p |= (1u << (r * 8));
                if (fabsf(ybn - 2.0f) < TAU) {
                    unsigned int idx = atomicAdd(&lcnt, 1u);   // LDS atomic
                    if (idx < BCAP) {
                        int j = jtw * 128 + colb + fn * 16 + lr;
                        recsB[(size_t)blk * BCAP + idx] =
                            ((unsigned)z << 24) | ((unsigned)o << 14) | (unsigned)j;
                    }
                }
            }
            pk[fm][fn] = p;
        }

    // shfl-transpose pack -> direct blob stores
#pragma unroll
    for (int fnPair = 0; fnPair < 2; ++fnPair) {
        unsigned int got[4];
#pragma unroll
        for (int t = 0; t < 4; ++t) {
            int sel = (kgl + t) & 3;
            int sfm = sel >> 1, sfn = (sel & 1) * 2 + fnPair;
            unsigned int send =
                sfm == 0 ? (sfn == 0 ? pk[0][0] : sfn == 1 ? pk[0][1] : sfn == 2 ? pk[0][2] : pk[0][3])
                         : (sfn == 0 ? pk[1][0] : sfn == 1 ? pk[1][1] : sfn == 2 ? pk[1][2] : pk[1][3]);
            int src = (((kgl - t) & 3) << 4) + lr;
            got[t] = (unsigned int)__shfl((int)send, src);
        }
        unsigned int part[4];
#pragma unroll
        for (int j = 0; j < 4; ++j) {
            int tsel = (kgl - j) & 3;
            part[j] = tsel == 0 ? got[0] : tsel == 1 ? got[1]
                    : tsel == 2 ? got[2] : got[3];
        }
        int4v chunk = (int4v){(int)part[0], (int)part[1], (int)part[2], (int)part[3]};
        int kg2 = wm * 2 + (kgl >> 1);
        int col = colb + ((kgl & 1) * 2 + fnPair) * 16 + lr;
        size_t off = (size_t)(jtw * KT_N + mt) * TILE_B + (size_t)kg2 * 2048 + (size_t)col * 16;
        *(int4v*)(sblob + off) = chunk;
    }
    __syncthreads();
    if (tid == 0) {
        unsigned int c = lcnt;
        cntArr[blk] = c > BCAP ? BCAP : c;
    }
}

// ---------------------------------------------------------------------------
// Pass-2 fixup over per-block record regions, SLOT-MAJOR pair distribution
// (slot = p / NBLK). Bit-exact numpy fp32 re-resolution (skip-zero exact).
// ---------------------------------------------------------------------------
__global__ __launch_bounds__(256) void fixup(
    const char* __restrict__ xs,
    const float* __restrict__ wq, const float* __restrict__ wk, const float* __restrict__ wv,
    const float* __restrict__ qg, const float* __restrict__ qb, const float* __restrict__ qm, const float* __restrict__ qv,
    const float* __restrict__ kg, const float* __restrict__ kb2, const float* __restrict__ km, const float* __restrict__ kvr,
    const float* __restrict__ vg, const float* __restrict__ vb, const float* __restrict__ vm, const float* __restrict__ vv,
    char* __restrict__ sq, char* __restrict__ sk, char* __restrict__ sv,
    const unsigned int* __restrict__ cntArr, const unsigned int* __restrict__ recsB)
{
#pragma clang fp contract(off)
    __shared__ float cw[4][C_DIM];
    const int lane = threadIdx.x & 63;
    const int wvid = threadIdx.x >> 6;
    const int gwave = blockIdx.x * 4 + wvid;
    const int nwaves = gridDim.x * 4;
    const int npairs = NBLK * BCAP;

    for (int p = gwave; p < npairs; p += nwaves) {
        int slot = p / NBLK;            // slow index: populated slots first
        int reg  = p - slot * NBLK;
        if ((unsigned)slot >= cntArr[reg]) continue;
        unsigned int rec = recsB[(size_t)reg * BCAP + slot];
        int plane = rec >> 24, o = (rec >> 14) & 1023, j = rec & 16383;
        int jt = j >> 7, col = j & 127;
        const float* w = plane == 0 ? wq : plane == 1 ? wk : wv;
        int base = 0;
#pragma unroll
        for (int cc = 0; cc < 12; ++cc) {
            int c = cc * 64 + lane;
            char s = xs[(size_t)(jt * KT_N + (c >> 6)) * TILE_B
                        + ((c >> 4) & 3) * 2048 + col * 16 + (c & 15)];
            float wvv = w[(size_t)o * C_DIM + c];
            bool act = (s != 0);
            unsigned long long m = __ballot(act);
            int pos = __popcll(m & ((1ull << lane) - 1ull));
            if (act) cw[wvid][base + pos] = wvv;
            base += __popcll(m);
        }
        __builtin_amdgcn_s_waitcnt(0);       // wave-coherent LDS
        if (lane == 0) {
            float s = 0.0f;
            for (int i = 0; i < base; ++i) s = s + cw[wvid][i];   // strict order
            const float* g  = plane == 0 ? qg : plane == 1 ? kg : vg;
            const float* be = plane == 0 ? qb : plane == 1 ? kb2 : vb;
            const float* me = plane == 0 ? qm : plane == 1 ? km : vm;
            const float* va = plane == 0 ? qv : plane == 1 ? kvr : vv;
            float invv = g[o] / sqrtf(va[o] + 1e-5f);
            float t1 = me[o] * invv;
            float bias = be[o] - t1;
            float t3 = s * invv;
            float ybn = t3 + bias;
            char spv = (ybn >= 2.0f) ? (char)1 : (char)0;
            char* blob = plane == 0 ? sq : plane == 1 ? sk : sv;
            blob[(size_t)(jt * KT_N + (o >> 6)) * TILE_B
                 + ((o >> 4) & 3) * 2048 + col * 16 + (o & 15)] = spv;
        }
    }
}

// ---------------------------------------------------------------------------
// maskb[b][c] = OR_n (sk & sv), bytes {0,1}
// ---------------------------------------------------------------------------
__global__ __launch_bounds__(256) void kv_mask_blob(
    const char* __restrict__ sk, const char* __restrict__ sv,
    unsigned char* __restrict__ maskb)
{
    const int kt = blockIdx.x, b = blockIdx.y;
    const int t = threadIdx.x;
    const int kgc = t >> 6;
    const int col0 = (t & 63) * 2;
    __shared__ unsigned int lmask[4][4];
    if (t < 16) lmask[t >> 2][t & 3] = 0;
    __syncthreads();
    uint4 acc = make_uint4(0, 0, 0, 0);
    for (int jti = 0; jti < 8; ++jti) {
        size_t base = (size_t)((b * 8 + jti) * KT_N + kt) * TILE_B + kgc * 2048;
#pragma unroll
        for (int cc = 0; cc < 2; ++cc) {
            uint4 kk = *(const uint4*)(sk + base + (size_t)(col0 + cc) * 16);
            uint4 vv = *(const uint4*)(sv + base + (size_t)(col0 + cc) * 16);
            acc.x |= (kk.x & vv.x); acc.y |= (kk.y & vv.y);
            acc.z |= (kk.z & vv.z); acc.w |= (kk.w & vv.w);
        }
    }
    if (acc.x) atomicOr(&lmask[kgc][0], acc.x);
    if (acc.y) atomicOr(&lmask[kgc][1], acc.y);
    if (acc.z) atomicOr(&lmask[kgc][2], acc.z);
    if (acc.w) atomicOr(&lmask[kgc][3], acc.w);
    __syncthreads();
    if (t < 64) {
        int kg2 = t >> 4, e = t & 15;
        unsigned int dw = lmask[kg2][e >> 2];
        unsigned char byte = (dw >> ((e & 3) * 8)) & 0xFF;
        maskb[(size_t)b * C_DIM + kt * 64 + t] = byte ? 1 : 0;
    }
}

// ---------------------------------------------------------------------------
// Final projection: out = (wp·(sq & mask) + bp)*inv + bias + x
// Same 64x256 counted-vmcnt pipeline; mask pre-staged to LDS.
// ---------------------------------------------------------------------------
__global__ __launch_bounds__(512, 4) void final_mfma(
    const char* __restrict__ wblob, const char* __restrict__ sqblob,
    const unsigned char* __restrict__ maskb,
    const float* __restrict__ x, const float* __restrict__ bp,
    const float* __restrict__ invt, const float* __restrict__ biast,
    float* __restrict__ out)
{
    __shared__ char stage[2][24576];
    __shared__ char mlds[768];
    const int jt2 = blockIdx.x, mt = blockIdx.y;
    const int jt0 = jt2 * 2;
    const int tid = threadIdx.x;
    const int lane = tid & 63, wid = tid >> 6;
    const int wm = wid >> 2, wn = wid & 3;
    const int lr = lane & 15, kgl = lane >> 4;
    const int b = jt0 >> 3;
    const float* invp  = invt  + 3 * C_DIM;
    const float* biasp = biast + 3 * C_DIM;

    const int mt128 = mt >> 1, mrow = (mt & 1) * 64;
    const int aIdx = tid & 255;
    const size_t aoff_src = (size_t)((tid < 256) ? 0 : PLANE_B)
                          + (aIdx >> 6) * 2048 + (size_t)(mrow + (aIdx & 63)) * 16;

#define STG(buf, ktA) do {                                                     \
        const char* Ab_ = wblob + (size_t)((ktA) * MT_N + mt128) * TILE_B;     \
        const char* B0_ = sqblob + (size_t)(jt0 * KT_N + (ktA)) * TILE_B;      \
        const char* B1_ = sqblob + (size_t)((jt0 + 1) * KT_N + (ktA)) * TILE_B;\
        char* d_ = stage[buf];                                                 \
        gload16(Ab_ + aoff_src,                d_ + tid * 16);                 \
        gload16(B0_ + (size_t)tid * 16,        d_ + 8192 + tid * 16);          \
        gload16(B1_ + (size_t)tid * 16,        d_ + 16384 + tid * 16);         \
    } while (0)

    int4v acch[2][4], accl[2][4];
#pragma unroll
    for (int a = 0; a < 2; ++a)
#pragma unroll
        for (int b2 = 0; b2 < 4; ++b2) {
            acch[a][b2] = (int4v){0, 0, 0, 0};
            accl[a][b2] = (int4v){0, 0, 0, 0};
        }

    if (tid < 48)
        *(int4v*)&mlds[tid * 16] = *(const int4v*)(maskb + (size_t)b * C_DIM + tid * 16);
    STG(0, 0);
    STG(1, 1);
    __syncthreads();                 // one-time full drain (mlds + stages 0,1)
    int cur = 0;
    const int arow = (wm * 32 + lr) * 16;
    const int bbase = 8192 + (wn >> 1) * 8192 + ((wn & 1) * 64) * 16;
    for (int kt = 0; kt < KT_N; ++kt) {
        if (kt + 1 < KT_N) asm volatile("s_waitcnt vmcnt(3)");
        else               asm volatile("s_waitcnt vmcnt(0)");
        __builtin_amdgcn_s_barrier();
        __builtin_amdgcn_sched_barrier(0);
        const char* st = stage[cur];
        int4v ah0 = *(const int4v*)&st[kgl * 1024 + arow];
        int4v ah1 = *(const int4v*)&st[kgl * 1024 + arow + 256];
        int4v al0 = *(const int4v*)&st[4096 + kgl * 1024 + arow];
        int4v al1 = *(const int4v*)&st[4096 + kgl * 1024 + arow + 256];
        int4v mp = *(const int4v*)&mlds[kt * 64 + kgl * 16];
        int4v bfr[4];
#pragma unroll
        for (int fn = 0; fn < 4; ++fn)
            bfr[fn] = *(const int4v*)&st[bbase + kgl * 2048 + (fn * 16 + lr) * 16];
        __builtin_amdgcn_sched_barrier(0);
        asm volatile("s_waitcnt lgkmcnt(0)");
        __builtin_amdgcn_sched_barrier(0);
        __builtin_amdgcn_s_barrier();
        if (kt + 2 < KT_N) STG(cur, kt + 2);
#pragma unroll
        for (int fn = 0; fn < 4; ++fn) bfr[fn] &= mp;
        __builtin_amdgcn_s_setprio(1);
#pragma unroll
        for (int fn = 0; fn < 4; ++fn) {
            acch[0][fn] = __builtin_amdgcn_mfma_i32_16x16x64_i8(ah0, bfr[fn], acch[0][fn], 0, 0, 0);
            acch[1][fn] = __builtin_amdgcn_mfma_i32_16x16x64_i8(ah1, bfr[fn], acch[1][fn], 0, 0, 0);
            accl[0][fn] = __builtin_amdgcn_mfma_i32_16x16x64_i8(al0, bfr[fn], accl[0][fn], 0, 0, 0);
            accl[1][fn] = __builtin_amdgcn_mfma_i32_16x16x64_i8(al1, bfr[fn], accl[1][fn], 0, 0, 0);
        }
        __builtin_amdgcn_s_setprio(0);
        cur ^= 1;
    }
#undef STG

    const int jtw = jt0 + (wn >> 1);
    const int n0 = (jtw & 7) * 128;
    const int colb = (wn & 1) * 64;
#pragma unroll
    for (int fm = 0; fm < 2; ++fm)
#pragma unroll
        for (int fn = 0; fn < 4; ++fn)
#pragma unroll
            for (int r = 0; r < 4; ++r) {
                int p = mt * 64 + wm * 32 + fm * 16 + kgl * 4 + r;
                int nl = colb + fn * 16 + lr;
                int vi = acch[fm][fn][r] * 256 + accl[fm][fn][r];
                float pre = (float)vi * 6.103515625e-05f;
                size_t idx = ((size_t)b * C_DIM + p) * NPIX + n0 + nl;
                out[idx] = (pre + bp[p]) * invp[p] + biasp[p] + x[idx];
            }
}

extern "C" void kernel_launch(void* const* d_in, const int* in_sizes, int n_in,
                              void* d_out, int out_size, void* d_ws, size_t ws_size,
                              hipStream_t stream) {
    const float* x  = (const float*)d_in[0];
    const float* wq = (const float*)d_in[1];
    const float* qg = (const float*)d_in[2];
    const float* qb = (const float*)d_in[3];
    const float* qm = (const float*)d_in[4];
    const float* qv = (const float*)d_in[5];
    const float* wk = (const float*)d_in[6];
    const float* kg = (const float*)d_in[7];
    const float* kb = (const float*)d_in[8];
    const float* km = (const float*)d_in[9];
    const float* kvv= (const float*)d_in[10];
    const float* wv = (const float*)d_in[11];
    const float* vg = (const float*)d_in[12];
    const float* vb = (const float*)d_in[13];
    const float* vm = (const float*)d_in[14];
    const float* vv = (const float*)d_in[15];
    const float* wp = (const float*)d_in[16];
    const float* bp = (const float*)d_in[17];
    const float* pg = (const float*)d_in[18];
    const float* pb = (const float*)d_in[19];
    const float* pm = (const float*)d_in[20];
    const float* pv = (const float*)d_in[21];

    const size_t SPIKE = (size_t)C_DIM * NTOT;       // bytes per spike blob
    char* sq  = (char*)d_ws;
    char* sk  = sq + SPIKE;
    char* sv  = sk + SPIKE;
    char* xs  = sv + SPIKE;
    char* wall = xs + SPIKE;                         // 4 sets x 2 planes
    unsigned char* maskb = (unsigned char*)(wall + (size_t)4 * 2 * PLANE_B);
    unsigned int* cntArr = (unsigned int*)(maskb + 16384);        // NBLK u32
    unsigned int* recsB  = cntArr + NBLK;                         // NBLK*BCAP u32
    float* invt  = (float*)(recsB + (size_t)NBLK * BCAP);
    float* biast = invt + 4 * C_DIM;
    char* wpb = wall + (size_t)3 * 2 * PLANE_B;

    prep_all<<<PREP_SPIKE_BLKS + PREP_W_BLKS + PREP_BN_BLKS, 256, 0, stream>>>(
        x, wq, wk, wv, wp,
        qg, qb, qm, qv, kg, kb, km, kvv, vg, vb, vm, vv, pg, pb, pm, pv,
        xs, wall, invt, biast);
    branch_mfma<<<dim3(JT2_N, MT2_N, 3), 512, 0, stream>>>(
        wall, xs, invt, biast, sq, cntArr, recsB);
    fixup<<<2048, 256, 0, stream>>>(xs, wq, wk, wv,
                                    qg, qb, qm, qv, kg, kb, km, kvv, vg, vb, vm, vv,
                                    sq, sk, sv, cntArr, recsB);
    kv_mask_blob<<<dim3(KT_N, B_DIM), 256, 0, stream>>>(sk, sv, maskb);
    final_mfma<<<dim3(JT2_N, MT2_N), 512, 0, stream>>>(
        wpb, sq, maskb, x, bp, invt, biast, (float*)d_out);
}